// Round 10
// baseline (66.723 us; speedup 1.0000x reference)
//
#include <hip/hip_runtime.h>

#define NN 4096
#define FIN 256
#define FOUT 64
#define NH 4
#define CAP 128    // max edges/row; Binomial(4096,0.01) P(>127) ~ 1e-30
#define HLDS 260   // padded h row stride (float4-aligned, bank-spread)

// ---------------------------------------------------------------------------
// K1: hprime. Block = 4 nodes x all 4 heads (wave = head). lane = (og, n_sub):
// n_sub = lane&3 (node), og = lane>>2 (o-quad: outputs og*4..og*4+4).
// Per f: 1 private-ish LDS h read + 1 b128 w read -> 4 FMA/lane (32/lane per
// 8-f chunk). No 64-lane broadcast, no s_load, acc = 4 VGPR.
// Also emits src/dst logits via og-reduction (shfl_xor over lane bits 2..5).
// ---------------------------------------------------------------------------
__global__ __launch_bounds__(256) void gat_hprime(
    const float* __restrict__ h, const float* __restrict__ w,
    const float* __restrict__ a_src, const float* __restrict__ a_dst,
    float* __restrict__ h_prime, float* __restrict__ src, float* __restrict__ dst)
{
    const int t = threadIdx.x, hh = t >> 6, lane = t & 63;
    const int n0 = blockIdx.x * 4;
    const int n_sub = lane & 3, og = lane >> 2;

    __shared__ float hs[4 * HLDS];
    {   // stage 4 h rows (1024 f32 = 256 float4), coalesced
        const int n = t >> 6, f4 = t & 63;
        *(float4*)&hs[n * HLDS + f4 * 4] =
            *(const float4*)(h + (size_t)(n0 + n) * FIN + f4 * 4);
    }
    __syncthreads();

    const float* wp = w + (size_t)hh * FIN * FOUT + og * 4;
    float4 acc = make_float4(0.f, 0.f, 0.f, 0.f);

#pragma unroll 2
    for (int f = 0; f < FIN; f += 8) {
        const float4 hq0 = *(const float4*)&hs[n_sub * HLDS + f];
        const float4 hq1 = *(const float4*)&hs[n_sub * HLDS + f + 4];
        float4 wq[8];
#pragma unroll
        for (int j = 0; j < 8; ++j)
            wq[j] = *(const float4*)(wp + (size_t)(f + j) * FOUT);
        const float hv[8] = {hq0.x, hq0.y, hq0.z, hq0.w,
                             hq1.x, hq1.y, hq1.z, hq1.w};
#pragma unroll
        for (int j = 0; j < 8; ++j) {
            acc.x = fmaf(hv[j], wq[j].x, acc.x);
            acc.y = fmaf(hv[j], wq[j].y, acc.y);
            acc.z = fmaf(hv[j], wq[j].z, acc.z);
            acc.w = fmaf(hv[j], wq[j].w, acc.w);
        }
    }

    // h_prime store: per lane one float4, contiguous over og
    *(float4*)(h_prime + ((size_t)hh * NN + n0 + n_sub) * FOUT + og * 4) = acc;

    // src/dst logits: partial over my o-quad, reduce over og (lane bits 2..5)
    const float4 as4 = *(const float4*)(a_src + hh * FOUT + og * 4);
    const float4 ad4 = *(const float4*)(a_dst + hh * FOUT + og * 4);
    float ps = acc.x * as4.x + acc.y * as4.y + acc.z * as4.z + acc.w * as4.w;
    float pd = acc.x * ad4.x + acc.y * ad4.y + acc.z * ad4.z + acc.w * ad4.w;
#pragma unroll
    for (int off = 4; off <= 32; off <<= 1) {
        ps += __shfl_xor(ps, off, 64);
        pd += __shfl_xor(pd, off, 64);
    }
    if (og == 0) {
        src[hh * NN + n0 + n_sub] = ps;
        dst[hh * NN + n0 + n_sub] = pd;
    }
}

// ---------------------------------------------------------------------------
// K2: adj (64MB int32) -> ballot bitmask (2MB). Grid-stride pure stream,
// no atomics, no prefix, no ordering deps.
// Encoding: bits[row][it*4+k] bit l <-> col = it*256 + 4*l + k.
// ---------------------------------------------------------------------------
__global__ __launch_bounds__(256) void gat_scanbits(
    const int* __restrict__ adj, unsigned long long* __restrict__ bits)
{
    const int lane = threadIdx.x & 63;
    const int nvec = NN * NN / 4;                  // 4,194,304 int4
    const int step = 2048 * 256;
    for (int g = blockIdx.x * 256 + threadIdx.x; g < nvec; g += step) {
        const int4 a = ((const int4*)adj)[g];
        const unsigned long long b0 = __ballot(a.x != 0);
        const unsigned long long b1 = __ballot(a.y != 0);
        const unsigned long long b2 = __ballot(a.z != 0);
        const unsigned long long b3 = __ballot(a.w != 0);
        const int row = g >> 10;                   // wave-uniform
        const int it  = (g >> 6) & 15;             // chunk within row
        unsigned long long mk = b0;
        mk = ((lane & 3) == 1) ? b1 : mk;
        mk = ((lane & 3) == 2) ? b2 : mk;
        mk = ((lane & 3) == 3) ? b3 : mk;
        if (lane < 4) bits[(size_t)row * 64 + it * 4 + lane] = mk;
    }
}

// ---------------------------------------------------------------------------
// K3: attn from bitmask (r9 structure). Block = row i; wave 0 decodes mask
// into LDS edge list; scores; per-head softmax (wave = head); 8-deep gather.
// ---------------------------------------------------------------------------
__global__ __launch_bounds__(256) void gat_attn(
    const unsigned long long* __restrict__ bits,
    const float* __restrict__ h_prime, const float* __restrict__ src,
    const float* __restrict__ dst, const float* __restrict__ bias,
    float* __restrict__ out)
{
    const int i = blockIdx.x, t = threadIdx.x, wv = t >> 6, lane = t & 63;

    __shared__ int   idx_l[CAP];
    __shared__ float sc[NH][CAP];
    __shared__ int   cnt;
    __shared__ float inv_sum[NH];

    if (wv == 0) {
        unsigned long long m = bits[(size_t)i * 64 + lane];
        const int c = __popcll(m);
        int pre = c;
#pragma unroll
        for (int off = 1; off < 64; off <<= 1) {
            const int nb = __shfl_up(pre, off, 64);
            if (lane >= off) pre += nb;
        }
        int p = pre - c;
        const int cb = (lane >> 2) * 256 + (lane & 3);
        while (m) {
            const int bpos = __ffsll((unsigned long long)m) - 1;
            if (p < CAP) idx_l[p] = cb + 4 * bpos;
            ++p;
            m &= m - 1;
        }
        if (lane == 63) cnt = pre;
    }
    __syncthreads();

    const int count = min(cnt, CAP);
    const int cpad  = (count + 7) & ~7;

    if (t < count) {
        const int j = idx_l[t];
#pragma unroll
        for (int hh = 0; hh < NH; ++hh) {
            const float v = src[hh * NN + i] + dst[hh * NN + j];
            sc[hh][t] = (v >= 0.f) ? v : 0.2f * v;   // leaky_relu(0.2)
        }
    } else if (t < cpad) {
        idx_l[t] = 0;
#pragma unroll
        for (int hh = 0; hh < NH; ++hh) sc[hh][t] = 0.f;
    }
    __syncthreads();

    {
        float m = -3.4e38f;
        for (int p = lane; p < count; p += 64) m = fmaxf(m, sc[wv][p]);
#pragma unroll
        for (int off = 32; off >= 1; off >>= 1) m = fmaxf(m, __shfl_xor(m, off, 64));
        float e = 0.f;
        for (int p = lane; p < count; p += 64) {
            const float v = __expf(sc[wv][p] - m);
            sc[wv][p] = v;
            e += v;
        }
#pragma unroll
        for (int off = 32; off >= 1; off >>= 1) e += __shfl_xor(e, off, 64);
        if (lane == 0) inv_sum[wv] = 1.f / e;
    }
    __syncthreads();

    float accv = 0.f;
    const float* hp = h_prime + (size_t)(wv * NN) * FOUT + lane;
    for (int p0 = 0; p0 < cpad; p0 += 8) {
        int jj[8]; float vv[8]; float ww[8];
#pragma unroll
        for (int k = 0; k < 8; ++k) jj[k] = idx_l[p0 + k];
#pragma unroll
        for (int k = 0; k < 8; ++k) vv[k] = hp[(size_t)jj[k] * FOUT];
#pragma unroll
        for (int k = 0; k < 8; ++k) ww[k] = sc[wv][p0 + k];
#pragma unroll
        for (int k = 0; k < 8; ++k) accv = fmaf(ww[k], vv[k], accv);
    }
    out[(size_t)i * (NH * FOUT) + wv * FOUT + lane] = accv * inv_sum[wv] + bias[lane];
}

extern "C" void kernel_launch(void* const* d_in, const int* in_sizes, int n_in,
                              void* d_out, int out_size, void* d_ws, size_t ws_size,
                              hipStream_t stream) {
    const float* h     = (const float*)d_in[0];
    const int*   adj   = (const int*)d_in[1];
    const float* w     = (const float*)d_in[2];
    const float* a_src = (const float*)d_in[3];
    const float* a_dst = (const float*)d_in[4];
    const float* bias  = (const float*)d_in[5];
    float* out = (float*)d_out;

    float* wsf     = (float*)d_ws;
    float* h_prime = wsf;                        // NH*NN*FOUT floats = 4 MB
    float* src     = h_prime + NH * NN * FOUT;   // NH*NN floats
    float* dst     = src + NH * NN;              // NH*NN floats
    unsigned long long* bits = (unsigned long long*)(dst + NH * NN);  // 2 MB

    gat_hprime<<<NN / 4, 256, 0, stream>>>(h, w, a_src, a_dst, h_prime, src, dst);
    gat_scanbits<<<2048, 256, 0, stream>>>(adj, bits);
    gat_attn<<<NN, 256, 0, stream>>>(bits, h_prime, src, dst, bias, out);
}

// Round 11
// 42.281 us; speedup vs baseline: 1.5781x; 1.5781x over previous
//
#include <hip/hip_runtime.h>

#define NN 4096
#define FIN 256
#define FOUT 64
#define NH 4
#define CAP 128    // max edges/row; Binomial(4096,0.01) P(>127) ~ 1e-30
#define HPAD 264   // padded bf16 row stride (keeps b128 reads ~2-way, free)

typedef __attribute__((ext_vector_type(8))) short bf16x8;
typedef __attribute__((ext_vector_type(4))) float f32x4;

__device__ __forceinline__ unsigned short f2bf(float f) {   // RNE f32->bf16
    unsigned u = __float_as_uint(f);
    u = (u + 0x7fff + ((u >> 16) & 1)) >> 16;
    return (unsigned short)u;
}

// ---------------------------------------------------------------------------
// K1: MFMA hprime. Block = (node-group of 64) x (one head). 256 blocks.
// Stage h-tile + w[head] into LDS as bf16 (converted in-flight), then each
// wave computes a 16x64 C-tile with 32x mfma_f32_16x16x32_bf16.
// A-frag: hs[row][k] contiguous 8 bf16 (row = lane&15, kchunk = lane>>4).
// B-frag: ws[col][k] contiguous 8 bf16 (B^T form, col = lane&15).
// C:      col = lane&15, row = (lane>>4)*4 + reg   [m89-verified layout]
// src/dst logits reduced from acc in-register (shfl over lane&15).
// ---------------------------------------------------------------------------
__global__ __launch_bounds__(256) void gat_mfma(
    const float* __restrict__ h, const float* __restrict__ w,
    const float* __restrict__ a_src, const float* __restrict__ a_dst,
    float* __restrict__ h_prime, float* __restrict__ src, float* __restrict__ dst)
{
    const int b = blockIdx.x, t = threadIdx.x;
    const int head = b & 3, n0 = (b >> 2) * 64;
    const int wv = t >> 6, lane = t & 63;
    const int lrow = lane & 15, lk8 = lane >> 4;

    __shared__ unsigned short hs[64 * HPAD];   // 33 KB: h-tile bf16
    __shared__ unsigned short ws[64 * HPAD];   // 33 KB: w[head]^T bf16

    // stage h rows n0..n0+64 (fp32 -> bf16), coalesced float4
#pragma unroll
    for (int i = 0; i < 16; ++i) {
        const int idx = t + i * 256;           // 4096 float4-chunks
        const int row = idx >> 6, f4 = idx & 63;
        const float4 v = *(const float4*)(h + (size_t)(n0 + row) * FIN + f4 * 4);
        ushort4 o;
        o.x = f2bf(v.x); o.y = f2bf(v.y); o.z = f2bf(v.z); o.w = f2bf(v.w);
        *(ushort4*)&hs[row * HPAD + f4 * 4] = o;
    }
    // stage w[head] transposed: ws[o][k] = w[head][k][o]
    {
        const int kb = t >> 4, o4 = t & 15;
#pragma unroll
        for (int i = 0; i < 16; ++i) {
            const int k = kb + i * 16;
            const float4 v = *(const float4*)(w + ((size_t)head * FIN + k) * FOUT + o4 * 4);
            ws[(o4 * 4 + 0) * HPAD + k] = f2bf(v.x);
            ws[(o4 * 4 + 1) * HPAD + k] = f2bf(v.y);
            ws[(o4 * 4 + 2) * HPAD + k] = f2bf(v.z);
            ws[(o4 * 4 + 3) * HPAD + k] = f2bf(v.w);
        }
    }
    __syncthreads();

    // A-fragments for this wave's 16 nodes, all 8 K-steps, held in regs
    bf16x8 a[8];
#pragma unroll
    for (int ks = 0; ks < 8; ++ks)
        a[ks] = *(const bf16x8*)&hs[(wv * 16 + lrow) * HPAD + ks * 32 + lk8 * 8];

    f32x4 acc[4] = {{0.f,0.f,0.f,0.f},{0.f,0.f,0.f,0.f},
                    {0.f,0.f,0.f,0.f},{0.f,0.f,0.f,0.f}};
#pragma unroll
    for (int ks = 0; ks < 8; ++ks) {
#pragma unroll
        for (int nt = 0; nt < 4; ++nt) {
            const bf16x8 bf = *(const bf16x8*)&ws[(nt * 16 + lrow) * HPAD + ks * 32 + lk8 * 8];
            acc[nt] = __builtin_amdgcn_mfma_f32_16x16x32_bf16(a[ks], bf, acc[nt], 0, 0, 0);
        }
    }

    // C store: row m = wv*16 + lk8*4 + r, col = nt*16 + lrow
    const int mbase = n0 + wv * 16 + lk8 * 4;
#pragma unroll
    for (int nt = 0; nt < 4; ++nt)
#pragma unroll
        for (int r = 0; r < 4; ++r)
            h_prime[((size_t)head * NN + mbase + r) * FOUT + nt * 16 + lrow] = acc[nt][r];

    // src/dst logits: psr[r] = sum_col acc * a_src[col]; reduce over lane&15
    float as_nt[4], ad_nt[4];
#pragma unroll
    for (int nt = 0; nt < 4; ++nt) {
        as_nt[nt] = a_src[head * FOUT + nt * 16 + lrow];
        ad_nt[nt] = a_dst[head * FOUT + nt * 16 + lrow];
    }
    float psr[4] = {0.f,0.f,0.f,0.f}, pdr[4] = {0.f,0.f,0.f,0.f};
#pragma unroll
    for (int nt = 0; nt < 4; ++nt)
#pragma unroll
        for (int r = 0; r < 4; ++r) {
            psr[r] = fmaf(acc[nt][r], as_nt[nt], psr[r]);
            pdr[r] = fmaf(acc[nt][r], ad_nt[nt], pdr[r]);
        }
#pragma unroll
    for (int r = 0; r < 4; ++r)
#pragma unroll
        for (int off = 1; off <= 8; off <<= 1) {
            psr[r] += __shfl_xor(psr[r], off, 64);
            pdr[r] += __shfl_xor(pdr[r], off, 64);
        }
    if (lrow == 0)
#pragma unroll
        for (int r = 0; r < 4; ++r) {
            src[head * NN + mbase + r] = psr[r];
            dst[head * NN + mbase + r] = pdr[r];
        }
}

// ---------------------------------------------------------------------------
// K2: adj (64MB int32) -> ballot bitmask (2MB). Grid-stride pure stream.
// Encoding: bits[row][it*4+k] bit l <-> col = it*256 + 4*l + k.
// ---------------------------------------------------------------------------
__global__ __launch_bounds__(256) void gat_scanbits(
    const int* __restrict__ adj, unsigned long long* __restrict__ bits)
{
    const int lane = threadIdx.x & 63;
    const int nvec = NN * NN / 4;
    const int step = 2048 * 256;
    for (int g = blockIdx.x * 256 + threadIdx.x; g < nvec; g += step) {
        const int4 a = ((const int4*)adj)[g];
        const unsigned long long b0 = __ballot(a.x != 0);
        const unsigned long long b1 = __ballot(a.y != 0);
        const unsigned long long b2 = __ballot(a.z != 0);
        const unsigned long long b3 = __ballot(a.w != 0);
        const int row = g >> 10;
        const int it  = (g >> 6) & 15;
        unsigned long long mk = b0;
        mk = ((lane & 3) == 1) ? b1 : mk;
        mk = ((lane & 3) == 2) ? b2 : mk;
        mk = ((lane & 3) == 3) ? b3 : mk;
        if (lane < 4) bits[(size_t)row * 64 + it * 4 + lane] = mk;
    }
}

// ---------------------------------------------------------------------------
// K3: attn from bitmask. Block = row i; wave 0 decodes mask into LDS edge
// list; scores; per-head softmax (wave = head); 8-deep batched gather.
// ---------------------------------------------------------------------------
__global__ __launch_bounds__(256) void gat_attn(
    const unsigned long long* __restrict__ bits,
    const float* __restrict__ h_prime, const float* __restrict__ src,
    const float* __restrict__ dst, const float* __restrict__ bias,
    float* __restrict__ out)
{
    const int i = blockIdx.x, t = threadIdx.x, wv = t >> 6, lane = t & 63;

    __shared__ int   idx_l[CAP];
    __shared__ float sc[NH][CAP];
    __shared__ int   cnt;
    __shared__ float inv_sum[NH];

    if (wv == 0) {
        unsigned long long m = bits[(size_t)i * 64 + lane];
        const int c = __popcll(m);
        int pre = c;
#pragma unroll
        for (int off = 1; off < 64; off <<= 1) {
            const int nb = __shfl_up(pre, off, 64);
            if (lane >= off) pre += nb;
        }
        int p = pre - c;
        const int cb = (lane >> 2) * 256 + (lane & 3);
        while (m) {
            const int bpos = __ffsll((unsigned long long)m) - 1;
            if (p < CAP) idx_l[p] = cb + 4 * bpos;
            ++p;
            m &= m - 1;
        }
        if (lane == 63) cnt = pre;
    }
    __syncthreads();

    const int count = min(cnt, CAP);
    const int cpad  = (count + 7) & ~7;

    if (t < count) {
        const int j = idx_l[t];
#pragma unroll
        for (int hh = 0; hh < NH; ++hh) {
            const float v = src[hh * NN + i] + dst[hh * NN + j];
            sc[hh][t] = (v >= 0.f) ? v : 0.2f * v;   // leaky_relu(0.2)
        }
    } else if (t < cpad) {
        idx_l[t] = 0;
#pragma unroll
        for (int hh = 0; hh < NH; ++hh) sc[hh][t] = 0.f;
    }
    __syncthreads();

    {
        float m = -3.4e38f;
        for (int p = lane; p < count; p += 64) m = fmaxf(m, sc[wv][p]);
#pragma unroll
        for (int off = 32; off >= 1; off >>= 1) m = fmaxf(m, __shfl_xor(m, off, 64));
        float e = 0.f;
        for (int p = lane; p < count; p += 64) {
            const float v = __expf(sc[wv][p] - m);
            sc[wv][p] = v;
            e += v;
        }
#pragma unroll
        for (int off = 32; off >= 1; off >>= 1) e += __shfl_xor(e, off, 64);
        if (lane == 0) inv_sum[wv] = 1.f / e;
    }
    __syncthreads();

    float accv = 0.f;
    const float* hp = h_prime + (size_t)(wv * NN) * FOUT + lane;
    for (int p0 = 0; p0 < cpad; p0 += 8) {
        int jj[8]; float vv[8]; float ww[8];
#pragma unroll
        for (int k = 0; k < 8; ++k) jj[k] = idx_l[p0 + k];
#pragma unroll
        for (int k = 0; k < 8; ++k) vv[k] = hp[(size_t)jj[k] * FOUT];
#pragma unroll
        for (int k = 0; k < 8; ++k) ww[k] = sc[wv][p0 + k];
#pragma unroll
        for (int k = 0; k < 8; ++k) accv = fmaf(ww[k], vv[k], accv);
    }
    out[(size_t)i * (NH * FOUT) + wv * FOUT + lane] = accv * inv_sum[wv] + bias[lane];
}

extern "C" void kernel_launch(void* const* d_in, const int* in_sizes, int n_in,
                              void* d_out, int out_size, void* d_ws, size_t ws_size,
                              hipStream_t stream) {
    const float* h     = (const float*)d_in[0];
    const int*   adj   = (const int*)d_in[1];
    const float* w     = (const float*)d_in[2];
    const float* a_src = (const float*)d_in[3];
    const float* a_dst = (const float*)d_in[4];
    const float* bias  = (const float*)d_in[5];
    float* out = (float*)d_out;

    float* wsf     = (float*)d_ws;
    float* h_prime = wsf;                        // NH*NN*FOUT floats = 4 MB
    float* src     = h_prime + NH * NN * FOUT;   // NH*NN floats
    float* dst     = src + NH * NN;              // NH*NN floats
    unsigned long long* bits = (unsigned long long*)(dst + NH * NN);  // 2 MB

    gat_mfma<<<256, 256, 0, stream>>>(h, w, a_src, a_dst, h_prime, src, dst);
    gat_scanbits<<<2048, 256, 0, stream>>>(adj, bits);
    gat_attn<<<NN, 256, 0, stream>>>(bits, h_prime, src, dst, bias, out);
}

// Round 12
// 37.306 us; speedup vs baseline: 1.7885x; 1.1333x over previous
//
#include <hip/hip_runtime.h>

#define NN 4096
#define FIN 256
#define FOUT 64
#define NH 4
#define CAP 128    // max edges/row; Binomial(4096,0.01) P(>127) ~ 1e-30
#define HPAD 264   // padded bf16 row stride (16B-aligned rows)
#define MFB 256    // mfma blocks (64 nodes x 1 head each) -- FIRST in grid
#define CPB 1024   // compress blocks: 4 rows each (one wave per row)

typedef __attribute__((ext_vector_type(8))) short bf16x8;
typedef __attribute__((ext_vector_type(4))) float f32x4;

__device__ __forceinline__ unsigned short f2bf(float f) {   // RNE f32->bf16
    unsigned u = __float_as_uint(f);
    u = (u + 0x7fff + ((u >> 16) & 1)) >> 16;
    return (unsigned short)u;
}

// ---------------------------------------------------------------------------
// K1 (fused, independent block ranges; mfma blocks first so both types are
// co-resident and the adj stream overlaps MFMA work):
//  [0,MFB):      MFMA hprime: block = 64 nodes x 1 head. h-tile staged
//                coalesced to LDS bf16; w staged as fragment-linear granules
//                (conflict-free b128 LDS writes/reads). 32 MFMA per wave.
//                src/dst logits reduced from acc in-register.
//  [MFB,+CPB):   adj (64MB) -> ballot bitmask (2MB). One wave per row,
//                16 int4 loads in flight, no atomics.
// ---------------------------------------------------------------------------
__global__ __launch_bounds__(256) void gat_prep(
    const float* __restrict__ h, const int* __restrict__ adj,
    const float* __restrict__ w, const float* __restrict__ a_src,
    const float* __restrict__ a_dst,
    float* __restrict__ h_prime, float* __restrict__ src, float* __restrict__ dst,
    unsigned long long* __restrict__ bits)
{
    const int b = blockIdx.x, t = threadIdx.x;
    const int wv = t >> 6, lane = t & 63;

    __shared__ __align__(16) unsigned short hs[64 * HPAD];  // 33 KB
    __shared__ bf16x8 bfrag[2048];                          // 32 KB

    if (b < MFB) {
        const int head = b & 3, n0 = (b >> 2) * 64;
        const int lrow = lane & 15, lk8 = lane >> 4;

        // ---- stage h rows n0..n0+63 (fp32 -> bf16), coalesced float4 ----
#pragma unroll
        for (int i = 0; i < 16; ++i) {
            const int idx = t + i * 256;           // 4096 float4-chunks
            const int row = idx >> 6, f4 = idx & 63;
            const float4 v = *(const float4*)(h + (size_t)(n0 + row) * FIN + f4 * 4);
            ushort4 o;
            o.x = f2bf(v.x); o.y = f2bf(v.y); o.z = f2bf(v.z); o.w = f2bf(v.w);
            *(ushort4*)&hs[row * HPAD + f4 * 4] = o;
        }
        // ---- stage w[head] as fragment-linear granules ----
        // granule g: lane_g = g&63, ks = (g>>6)&7, nt = g>>9
        // holds w[kbase..kbase+8][col], col = nt*16 + (lane_g&15),
        // kbase = ks*32 + ((lane_g>>4)&3)*8
#pragma unroll
        for (int i = 0; i < 8; ++i) {
            const int g = t + i * 256;
            const int lg = g & 63, ks = (g >> 6) & 7, nt = g >> 9;
            const int col = nt * 16 + (lg & 15);
            const int kbase = ks * 32 + (lg >> 4) * 8;
            const float* wp = w + ((size_t)head * FIN + kbase) * FOUT + col;
            union { bf16x8 v; unsigned short s[8]; } u;
#pragma unroll
            for (int j = 0; j < 8; ++j) u.s[j] = f2bf(wp[j * FOUT]);
            bfrag[g] = u.v;                        // b128, lane-consecutive
        }
        __syncthreads();

        // ---- A-fragments: wave's 16 nodes, all 8 K-steps ----
        bf16x8 a[8];
#pragma unroll
        for (int ks = 0; ks < 8; ++ks)
            a[ks] = *(const bf16x8*)&hs[(wv * 16 + lrow) * HPAD + ks * 32 + lk8 * 8];

        f32x4 acc[4] = {{0.f,0.f,0.f,0.f},{0.f,0.f,0.f,0.f},
                        {0.f,0.f,0.f,0.f},{0.f,0.f,0.f,0.f}};
#pragma unroll
        for (int ks = 0; ks < 8; ++ks) {
#pragma unroll
            for (int nt = 0; nt < 4; ++nt)
                acc[nt] = __builtin_amdgcn_mfma_f32_16x16x32_bf16(
                              a[ks], bfrag[(nt * 8 + ks) * 64 + lane], acc[nt], 0, 0, 0);
        }

        // ---- C store: row m = wv*16 + lk8*4 + r, col = nt*16 + lrow ----
        const int mbase = n0 + wv * 16 + lk8 * 4;
#pragma unroll
        for (int nt = 0; nt < 4; ++nt)
#pragma unroll
            for (int r = 0; r < 4; ++r)
                h_prime[((size_t)head * NN + mbase + r) * FOUT + nt * 16 + lrow] = acc[nt][r];

        // ---- src/dst logits: reduce over col (lane&15) ----
        float as_nt[4], ad_nt[4];
#pragma unroll
        for (int nt = 0; nt < 4; ++nt) {
            as_nt[nt] = a_src[head * FOUT + nt * 16 + lrow];
            ad_nt[nt] = a_dst[head * FOUT + nt * 16 + lrow];
        }
        float psr[4] = {0.f,0.f,0.f,0.f}, pdr[4] = {0.f,0.f,0.f,0.f};
#pragma unroll
        for (int nt = 0; nt < 4; ++nt)
#pragma unroll
            for (int r = 0; r < 4; ++r) {
                psr[r] = fmaf(acc[nt][r], as_nt[nt], psr[r]);
                pdr[r] = fmaf(acc[nt][r], ad_nt[nt], pdr[r]);
            }
#pragma unroll
        for (int r = 0; r < 4; ++r)
#pragma unroll
            for (int off = 1; off <= 8; off <<= 1) {
                psr[r] += __shfl_xor(psr[r], off, 64);
                pdr[r] += __shfl_xor(pdr[r], off, 64);
            }
        if (lrow == 0)
#pragma unroll
            for (int r = 0; r < 4; ++r) {
                src[head * NN + mbase + r] = psr[r];
                dst[head * NN + mbase + r] = pdr[r];
            }
    } else {
        // ---- compress: one wave owns one row ----
        const int row = (b - MFB) * 4 + wv;
        const int4* arow = (const int4*)(adj + (size_t)row * NN);
        int4 buf[16];
#pragma unroll
        for (int it = 0; it < 16; ++it) buf[it] = arow[it * 64 + lane];

        unsigned long long* brow = bits + (size_t)row * 64;
#pragma unroll
        for (int it = 0; it < 16; ++it) {
            const unsigned long long b0 = __ballot(buf[it].x != 0);
            const unsigned long long b1 = __ballot(buf[it].y != 0);
            const unsigned long long b2 = __ballot(buf[it].z != 0);
            const unsigned long long b3 = __ballot(buf[it].w != 0);
            unsigned long long mk = b0;
            mk = ((lane & 3) == 1) ? b1 : mk;
            mk = ((lane & 3) == 2) ? b2 : mk;
            mk = ((lane & 3) == 3) ? b3 : mk;
            if (lane < 4) brow[it * 4 + lane] = mk;
        }
    }
}

// ---------------------------------------------------------------------------
// K2: attn from bitmask. Block = row i; wave 0 decodes mask into LDS edge
// list; scores; per-head softmax (wave = head); 8-deep batched gather.
// ---------------------------------------------------------------------------
__global__ __launch_bounds__(256) void gat_attn(
    const unsigned long long* __restrict__ bits,
    const float* __restrict__ h_prime, const float* __restrict__ src,
    const float* __restrict__ dst, const float* __restrict__ bias,
    float* __restrict__ out)
{
    const int i = blockIdx.x, t = threadIdx.x, wv = t >> 6, lane = t & 63;

    __shared__ int   idx_l[CAP];
    __shared__ float sc[NH][CAP];
    __shared__ int   cnt;
    __shared__ float inv_sum[NH];

    if (wv == 0) {
        unsigned long long m = bits[(size_t)i * 64 + lane];
        const int c = __popcll(m);
        int pre = c;
#pragma unroll
        for (int off = 1; off < 64; off <<= 1) {
            const int nb = __shfl_up(pre, off, 64);
            if (lane >= off) pre += nb;
        }
        int p = pre - c;
        const int cb = (lane >> 2) * 256 + (lane & 3);
        while (m) {
            const int bpos = __ffsll((unsigned long long)m) - 1;
            if (p < CAP) idx_l[p] = cb + 4 * bpos;
            ++p;
            m &= m - 1;
        }
        if (lane == 63) cnt = pre;
    }
    __syncthreads();

    const int count = min(cnt, CAP);
    const int cpad  = (count + 7) & ~7;

    if (t < count) {
        const int j = idx_l[t];
#pragma unroll
        for (int hh = 0; hh < NH; ++hh) {
            const float v = src[hh * NN + i] + dst[hh * NN + j];
            sc[hh][t] = (v >= 0.f) ? v : 0.2f * v;   // leaky_relu(0.2)
        }
    } else if (t < cpad) {
        idx_l[t] = 0;
#pragma unroll
        for (int hh = 0; hh < NH; ++hh) sc[hh][t] = 0.f;
    }
    __syncthreads();

    {
        float m = -3.4e38f;
        for (int p = lane; p < count; p += 64) m = fmaxf(m, sc[wv][p]);
#pragma unroll
        for (int off = 32; off >= 1; off >>= 1) m = fmaxf(m, __shfl_xor(m, off, 64));
        float e = 0.f;
        for (int p = lane; p < count; p += 64) {
            const float v = __expf(sc[wv][p] - m);
            sc[wv][p] = v;
            e += v;
        }
#pragma unroll
        for (int off = 32; off >= 1; off >>= 1) e += __shfl_xor(e, off, 64);
        if (lane == 0) inv_sum[wv] = 1.f / e;
    }
    __syncthreads();

    float accv = 0.f;
    const float* hp = h_prime + (size_t)(wv * NN) * FOUT + lane;
    for (int p0 = 0; p0 < cpad; p0 += 8) {
        int jj[8]; float vv[8]; float ww[8];
#pragma unroll
        for (int k = 0; k < 8; ++k) jj[k] = idx_l[p0 + k];
#pragma unroll
        for (int k = 0; k < 8; ++k) vv[k] = hp[(size_t)jj[k] * FOUT];
#pragma unroll
        for (int k = 0; k < 8; ++k) ww[k] = sc[wv][p0 + k];
#pragma unroll
        for (int k = 0; k < 8; ++k) accv = fmaf(ww[k], vv[k], accv);
    }
    out[(size_t)i * (NH * FOUT) + wv * FOUT + lane] = accv * inv_sum[wv] + bias[lane];
}

extern "C" void kernel_launch(void* const* d_in, const int* in_sizes, int n_in,
                              void* d_out, int out_size, void* d_ws, size_t ws_size,
                              hipStream_t stream) {
    const float* h     = (const float*)d_in[0];
    const int*   adj   = (const int*)d_in[1];
    const float* w     = (const float*)d_in[2];
    const float* a_src = (const float*)d_in[3];
    const float* a_dst = (const float*)d_in[4];
    const float* bias  = (const float*)d_in[5];
    float* out = (float*)d_out;

    float* wsf     = (float*)d_ws;
    float* h_prime = wsf;                        // NH*NN*FOUT floats = 4 MB
    float* src     = h_prime + NH * NN * FOUT;   // NH*NN floats
    float* dst     = src + NH * NN;              // NH*NN floats
    unsigned long long* bits = (unsigned long long*)(dst + NH * NN);  // 2 MB

    gat_prep<<<MFB + CPB, 256, 0, stream>>>(h, adj, w, a_src, a_dst,
                                            h_prime, src, dst, bits);
    gat_attn<<<NN, 256, 0, stream>>>(bits, h_prime, src, dst, bias, out);
}

// Round 13
// 35.996 us; speedup vs baseline: 1.8536x; 1.0364x over previous
//
#include <hip/hip_runtime.h>

#define NN 4096
#define FIN 256
#define FOUT 64
#define NH 4
#define CAP 128    // max edges/row; Binomial(4096,0.01) P(>127) ~ 1e-30
#define MFB 256    // mfma blocks (64 nodes x 1 head each) -- FIRST in grid
#define CPB 1024   // compress blocks: 4 rows each (one wave per row)

typedef __attribute__((ext_vector_type(8))) short bf16x8;
typedef __attribute__((ext_vector_type(4))) float f32x4;

__device__ __forceinline__ unsigned short f2bf(float f) {   // RNE f32->bf16
    unsigned u = __float_as_uint(f);
    u = (u + 0x7fff + ((u >> 16) & 1)) >> 16;
    return (unsigned short)u;
}

// ---------------------------------------------------------------------------
// K1 (fused, independent block ranges; mfma blocks first so both types are
// co-resident and the adj stream overlaps MFMA work). LDS = 32 KB only
// (bfrag) -> 5 blocks/CU, 20 waves/CU.
//  [0,MFB):    MFMA hprime: block = 64 nodes x 1 head. A-fragments loaded
//              DIRECTLY from global h (8 contiguous fp32 -> bf16x8, in-reg
//              convert, no LDS, no barrier for h). w staged as fragment-
//              linear granules in LDS (conflict-free b128). 32 MFMA/wave.
//              src/dst logits reduced from acc in-register.
//  [MFB,+CPB): adj (64MB) -> ballot bitmask (2MB). One wave per row.
// ---------------------------------------------------------------------------
__global__ __launch_bounds__(256) void gat_prep(
    const float* __restrict__ h, const int* __restrict__ adj,
    const float* __restrict__ w, const float* __restrict__ a_src,
    const float* __restrict__ a_dst,
    float* __restrict__ h_prime, float* __restrict__ src, float* __restrict__ dst,
    unsigned long long* __restrict__ bits)
{
    const int b = blockIdx.x, t = threadIdx.x;
    const int wv = t >> 6, lane = t & 63;

    __shared__ bf16x8 bfrag[2048];                          // 32 KB

    if (b < MFB) {
        const int head = b & 3, n0 = (b >> 2) * 64;
        const int lrow = lane & 15, lk8 = lane >> 4;

        // ---- A-fragments straight from global h (16 indep float4 loads) ----
        const float* hrow = h + (size_t)(n0 + wv * 16 + lrow) * FIN + lk8 * 8;
        bf16x8 a[8];
#pragma unroll
        for (int ks = 0; ks < 8; ++ks) {
            const float4 v0 = *(const float4*)(hrow + ks * 32);
            const float4 v1 = *(const float4*)(hrow + ks * 32 + 4);
            union { bf16x8 v; unsigned short s[8]; } u;
            u.s[0] = f2bf(v0.x); u.s[1] = f2bf(v0.y);
            u.s[2] = f2bf(v0.z); u.s[3] = f2bf(v0.w);
            u.s[4] = f2bf(v1.x); u.s[5] = f2bf(v1.y);
            u.s[6] = f2bf(v1.z); u.s[7] = f2bf(v1.w);
            a[ks] = u.v;
        }

        // ---- stage w[head] as fragment-linear granules ----
        // granule g: lane_g = g&63, ks = (g>>6)&7, nt = g>>9
        // holds w[kbase..kbase+8][col], col = nt*16 + (lane_g&15),
        // kbase = ks*32 + ((lane_g>>4)&3)*8
#pragma unroll
        for (int i = 0; i < 8; ++i) {
            const int g = t + i * 256;
            const int lg = g & 63, ks = (g >> 6) & 7, nt = g >> 9;
            const int col = nt * 16 + (lg & 15);
            const int kbase = ks * 32 + (lg >> 4) * 8;
            const float* wp = w + ((size_t)head * FIN + kbase) * FOUT + col;
            union { bf16x8 v; unsigned short s[8]; } u;
#pragma unroll
            for (int j = 0; j < 8; ++j) u.s[j] = f2bf(wp[j * FOUT]);
            bfrag[g] = u.v;                        // b128, lane-consecutive
        }
        __syncthreads();

        f32x4 acc[4] = {{0.f,0.f,0.f,0.f},{0.f,0.f,0.f,0.f},
                        {0.f,0.f,0.f,0.f},{0.f,0.f,0.f,0.f}};
#pragma unroll
        for (int ks = 0; ks < 8; ++ks) {
#pragma unroll
            for (int nt = 0; nt < 4; ++nt)
                acc[nt] = __builtin_amdgcn_mfma_f32_16x16x32_bf16(
                              a[ks], bfrag[(nt * 8 + ks) * 64 + lane], acc[nt], 0, 0, 0);
        }

        // ---- C store: row m = wv*16 + lk8*4 + r, col = nt*16 + lrow ----
        const int mbase = n0 + wv * 16 + lk8 * 4;
#pragma unroll
        for (int nt = 0; nt < 4; ++nt)
#pragma unroll
            for (int r = 0; r < 4; ++r)
                h_prime[((size_t)head * NN + mbase + r) * FOUT + nt * 16 + lrow] = acc[nt][r];

        // ---- src/dst logits: reduce over col (lane&15) ----
        float as_nt[4], ad_nt[4];
#pragma unroll
        for (int nt = 0; nt < 4; ++nt) {
            as_nt[nt] = a_src[head * FOUT + nt * 16 + lrow];
            ad_nt[nt] = a_dst[head * FOUT + nt * 16 + lrow];
        }
        float psr[4] = {0.f,0.f,0.f,0.f}, pdr[4] = {0.f,0.f,0.f,0.f};
#pragma unroll
        for (int nt = 0; nt < 4; ++nt)
#pragma unroll
            for (int r = 0; r < 4; ++r) {
                psr[r] = fmaf(acc[nt][r], as_nt[nt], psr[r]);
                pdr[r] = fmaf(acc[nt][r], ad_nt[nt], pdr[r]);
            }
#pragma unroll
        for (int r = 0; r < 4; ++r)
#pragma unroll
            for (int off = 1; off <= 8; off <<= 1) {
                psr[r] += __shfl_xor(psr[r], off, 64);
                pdr[r] += __shfl_xor(pdr[r], off, 64);
            }
        if (lrow == 0)
#pragma unroll
            for (int r = 0; r < 4; ++r) {
                src[head * NN + mbase + r] = psr[r];
                dst[head * NN + mbase + r] = pdr[r];
            }
    } else {
        // ---- compress: one wave owns one row ----
        const int row = (b - MFB) * 4 + wv;
        const int4* arow = (const int4*)(adj + (size_t)row * NN);
        int4 buf[16];
#pragma unroll
        for (int it = 0; it < 16; ++it) buf[it] = arow[it * 64 + lane];

        unsigned long long* brow = bits + (size_t)row * 64;
#pragma unroll
        for (int it = 0; it < 16; ++it) {
            const unsigned long long b0 = __ballot(buf[it].x != 0);
            const unsigned long long b1 = __ballot(buf[it].y != 0);
            const unsigned long long b2 = __ballot(buf[it].z != 0);
            const unsigned long long b3 = __ballot(buf[it].w != 0);
            unsigned long long mk = b0;
            mk = ((lane & 3) == 1) ? b1 : mk;
            mk = ((lane & 3) == 2) ? b2 : mk;
            mk = ((lane & 3) == 3) ? b3 : mk;
            if (lane < 4) brow[it * 4 + lane] = mk;
        }
    }
}

// ---------------------------------------------------------------------------
// K2: attn from bitmask. Block = row i; wave 0 decodes mask into LDS edge
// list; scores; per-head softmax (wave = head); 8-deep batched gather.
// ---------------------------------------------------------------------------
__global__ __launch_bounds__(256) void gat_attn(
    const unsigned long long* __restrict__ bits,
    const float* __restrict__ h_prime, const float* __restrict__ src,
    const float* __restrict__ dst, const float* __restrict__ bias,
    float* __restrict__ out)
{
    const int i = blockIdx.x, t = threadIdx.x, wv = t >> 6, lane = t & 63;

    __shared__ int   idx_l[CAP];
    __shared__ float sc[NH][CAP];
    __shared__ int   cnt;
    __shared__ float inv_sum[NH];

    if (wv == 0) {
        unsigned long long m = bits[(size_t)i * 64 + lane];
        const int c = __popcll(m);
        int pre = c;
#pragma unroll
        for (int off = 1; off < 64; off <<= 1) {
            const int nb = __shfl_up(pre, off, 64);
            if (lane >= off) pre += nb;
        }
        int p = pre - c;
        const int cb = (lane >> 2) * 256 + (lane & 3);
        while (m) {
            const int bpos = __ffsll((unsigned long long)m) - 1;
            if (p < CAP) idx_l[p] = cb + 4 * bpos;
            ++p;
            m &= m - 1;
        }
        if (lane == 63) cnt = pre;
    }
    __syncthreads();

    const int count = min(cnt, CAP);
    const int cpad  = (count + 7) & ~7;

    if (t < count) {
        const int j = idx_l[t];
#pragma unroll
        for (int hh = 0; hh < NH; ++hh) {
            const float v = src[hh * NN + i] + dst[hh * NN + j];
            sc[hh][t] = (v >= 0.f) ? v : 0.2f * v;   // leaky_relu(0.2)
        }
    } else if (t < cpad) {
        idx_l[t] = 0;
#pragma unroll
        for (int hh = 0; hh < NH; ++hh) sc[hh][t] = 0.f;
    }
    __syncthreads();

    {
        float m = -3.4e38f;
        for (int p = lane; p < count; p += 64) m = fmaxf(m, sc[wv][p]);
#pragma unroll
        for (int off = 32; off >= 1; off >>= 1) m = fmaxf(m, __shfl_xor(m, off, 64));
        float e = 0.f;
        for (int p = lane; p < count; p += 64) {
            const float v = __expf(sc[wv][p] - m);
            sc[wv][p] = v;
            e += v;
        }
#pragma unroll
        for (int off = 32; off >= 1; off >>= 1) e += __shfl_xor(e, off, 64);
        if (lane == 0) inv_sum[wv] = 1.f / e;
    }
    __syncthreads();

    float accv = 0.f;
    const float* hp = h_prime + (size_t)(wv * NN) * FOUT + lane;
    for (int p0 = 0; p0 < cpad; p0 += 8) {
        int jj[8]; float vv[8]; float ww[8];
#pragma unroll
        for (int k = 0; k < 8; ++k) jj[k] = idx_l[p0 + k];
#pragma unroll
        for (int k = 0; k < 8; ++k) vv[k] = hp[(size_t)jj[k] * FOUT];
#pragma unroll
        for (int k = 0; k < 8; ++k) ww[k] = sc[wv][p0 + k];
#pragma unroll
        for (int k = 0; k < 8; ++k) accv = fmaf(ww[k], vv[k], accv);
    }
    out[(size_t)i * (NH * FOUT) + wv * FOUT + lane] = accv * inv_sum[wv] + bias[lane];
}

extern "C" void kernel_launch(void* const* d_in, const int* in_sizes, int n_in,
                              void* d_out, int out_size, void* d_ws, size_t ws_size,
                              hipStream_t stream) {
    const float* h     = (const float*)d_in[0];
    const int*   adj   = (const int*)d_in[1];
    const float* w     = (const float*)d_in[2];
    const float* a_src = (const float*)d_in[3];
    const float* a_dst = (const float*)d_in[4];
    const float* bias  = (const float*)d_in[5];
    float* out = (float*)d_out;

    float* wsf     = (float*)d_ws;
    float* h_prime = wsf;                        // NH*NN*FOUT floats = 4 MB
    float* src     = h_prime + NH * NN * FOUT;   // NH*NN floats
    float* dst     = src + NH * NN;              // NH*NN floats
    unsigned long long* bits = (unsigned long long*)(dst + NH * NN);  // 2 MB

    gat_prep<<<MFB + CPB, 256, 0, stream>>>(h, adj, w, a_src, a_dst,
                                            h_prime, src, dst, bits);
    gat_attn<<<NN, 256, 0, stream>>>(bits, h_prime, src, dst, bias, out);
}

// Round 14
// 35.862 us; speedup vs baseline: 1.8605x; 1.0037x over previous
//
#include <hip/hip_runtime.h>

#define NN 4096
#define FIN 256
#define FOUT 64
#define NH 4
#define CAP 128    // max edges/row; Binomial(4096,0.01) P(>127) ~ 1e-30
#define MFB 256    // mfma blocks (64 nodes x 1 head each) -- FIRST in grid
#define CPB 1024   // compress blocks: 4 rows each (one wave per row)

typedef __attribute__((ext_vector_type(8))) short bf16x8;
typedef __attribute__((ext_vector_type(4))) float f32x4;

__device__ __forceinline__ unsigned short f2bf(float f) {   // RNE f32->bf16
    unsigned u = __float_as_uint(f);
    u = (u + 0x7fff + ((u >> 16) & 1)) >> 16;
    return (unsigned short)u;
}
__device__ __forceinline__ float bf2f(unsigned short s) {
    return __uint_as_float((unsigned)s << 16);
}

// ---------------------------------------------------------------------------
// K1 (fused, independent block ranges):
//  [0,MFB):    MFMA hprime: block = 64 nodes x 1 head. A-frags direct from
//              global h (in-reg bf16 convert); w staged fragment-linear in
//              LDS (32 KB). 32 MFMA/wave. OUTPUT: hb (bf16 h', 2 MB) +
//              sd (node-major src/dst float4 pairs).
//  [MFB,+CPB): adj (64MB) -> ballot bitmask (2MB). One wave per row.
// ---------------------------------------------------------------------------
__global__ __launch_bounds__(256) void gat_prep(
    const float* __restrict__ h, const int* __restrict__ adj,
    const float* __restrict__ w, const float* __restrict__ a_src,
    const float* __restrict__ a_dst,
    unsigned short* __restrict__ hb, float* __restrict__ sd,
    unsigned long long* __restrict__ bits)
{
    const int b = blockIdx.x, t = threadIdx.x;
    const int wv = t >> 6, lane = t & 63;

    __shared__ bf16x8 bfrag[2048];                          // 32 KB

    if (b < MFB) {
        const int head = b & 3, n0 = (b >> 2) * 64;
        const int lrow = lane & 15, lk8 = lane >> 4;

        // ---- A-fragments straight from global h (16 indep float4 loads) ----
        const float* hrow = h + (size_t)(n0 + wv * 16 + lrow) * FIN + lk8 * 8;
        bf16x8 a[8];
#pragma unroll
        for (int ks = 0; ks < 8; ++ks) {
            const float4 v0 = *(const float4*)(hrow + ks * 32);
            const float4 v1 = *(const float4*)(hrow + ks * 32 + 4);
            union { bf16x8 v; unsigned short s[8]; } u;
            u.s[0] = f2bf(v0.x); u.s[1] = f2bf(v0.y);
            u.s[2] = f2bf(v0.z); u.s[3] = f2bf(v0.w);
            u.s[4] = f2bf(v1.x); u.s[5] = f2bf(v1.y);
            u.s[6] = f2bf(v1.z); u.s[7] = f2bf(v1.w);
            a[ks] = u.v;
        }

        // ---- stage w[head] as fragment-linear granules ----
#pragma unroll
        for (int i = 0; i < 8; ++i) {
            const int g = t + i * 256;
            const int lg = g & 63, ks = (g >> 6) & 7, nt = g >> 9;
            const int col = nt * 16 + (lg & 15);
            const int kbase = ks * 32 + (lg >> 4) * 8;
            const float* wp = w + ((size_t)head * FIN + kbase) * FOUT + col;
            union { bf16x8 v; unsigned short s[8]; } u;
#pragma unroll
            for (int j = 0; j < 8; ++j) u.s[j] = f2bf(wp[j * FOUT]);
            bfrag[g] = u.v;
        }
        __syncthreads();

        f32x4 acc[4] = {{0.f,0.f,0.f,0.f},{0.f,0.f,0.f,0.f},
                        {0.f,0.f,0.f,0.f},{0.f,0.f,0.f,0.f}};
#pragma unroll
        for (int ks = 0; ks < 8; ++ks) {
#pragma unroll
            for (int nt = 0; nt < 4; ++nt)
                acc[nt] = __builtin_amdgcn_mfma_f32_16x16x32_bf16(
                              a[ks], bfrag[(nt * 8 + ks) * 64 + lane], acc[nt], 0, 0, 0);
        }

        // ---- C store (bf16): row m = wv*16 + lk8*4 + r, col = nt*16 + lrow ----
        const int mbase = n0 + wv * 16 + lk8 * 4;
#pragma unroll
        for (int nt = 0; nt < 4; ++nt)
#pragma unroll
            for (int r = 0; r < 4; ++r)
                hb[((size_t)head * NN + mbase + r) * FOUT + nt * 16 + lrow] =
                    f2bf(acc[nt][r]);

        // ---- src/dst logits -> node-major sd table ----
        float as_nt[4], ad_nt[4];
#pragma unroll
        for (int nt = 0; nt < 4; ++nt) {
            as_nt[nt] = a_src[head * FOUT + nt * 16 + lrow];
            ad_nt[nt] = a_dst[head * FOUT + nt * 16 + lrow];
        }
        float psr[4] = {0.f,0.f,0.f,0.f}, pdr[4] = {0.f,0.f,0.f,0.f};
#pragma unroll
        for (int nt = 0; nt < 4; ++nt)
#pragma unroll
            for (int r = 0; r < 4; ++r) {
                psr[r] = fmaf(acc[nt][r], as_nt[nt], psr[r]);
                pdr[r] = fmaf(acc[nt][r], ad_nt[nt], pdr[r]);
            }
#pragma unroll
        for (int r = 0; r < 4; ++r)
#pragma unroll
            for (int off = 1; off <= 8; off <<= 1) {
                psr[r] += __shfl_xor(psr[r], off, 64);
                pdr[r] += __shfl_xor(pdr[r], off, 64);
            }
        if (lrow == 0)
#pragma unroll
            for (int r = 0; r < 4; ++r) {
                sd[(size_t)(mbase + r) * 8 + head]     = psr[r];
                sd[(size_t)(mbase + r) * 8 + 4 + head] = pdr[r];
            }
    } else {
        // ---- compress: one wave owns one row ----
        const int row = (b - MFB) * 4 + wv;
        const int4* arow = (const int4*)(adj + (size_t)row * NN);
        int4 buf[16];
#pragma unroll
        for (int it = 0; it < 16; ++it) buf[it] = arow[it * 64 + lane];

        unsigned long long* brow = bits + (size_t)row * 64;
#pragma unroll
        for (int it = 0; it < 16; ++it) {
            const unsigned long long b0 = __ballot(buf[it].x != 0);
            const unsigned long long b1 = __ballot(buf[it].y != 0);
            const unsigned long long b2 = __ballot(buf[it].z != 0);
            const unsigned long long b3 = __ballot(buf[it].w != 0);
            unsigned long long mk = b0;
            mk = ((lane & 3) == 1) ? b1 : mk;
            mk = ((lane & 3) == 2) ? b2 : mk;
            mk = ((lane & 3) == 3) ? b3 : mk;
            if (lane < 4) brow[it * 4 + lane] = mk;
        }
    }
}

// ---------------------------------------------------------------------------
// K2: attn. Block = row i; wave 0 decodes mask into LDS edge list; scores
// via ONE float4 (all 4 heads) per edge from sd; per-head softmax (wave =
// head); 8-deep batched gather from bf16 hb (2 MB, L2-resident).
// ---------------------------------------------------------------------------
__global__ __launch_bounds__(256) void gat_attn(
    const unsigned long long* __restrict__ bits,
    const unsigned short* __restrict__ hb, const float* __restrict__ sd,
    const float* __restrict__ bias, float* __restrict__ out)
{
    const int i = blockIdx.x, t = threadIdx.x, wv = t >> 6, lane = t & 63;

    __shared__ int   idx_l[CAP];
    __shared__ float sc[NH][CAP];
    __shared__ int   cnt;
    __shared__ float inv_sum[NH];

    if (wv == 0) {
        unsigned long long m = bits[(size_t)i * 64 + lane];
        const int c = __popcll(m);
        int pre = c;
#pragma unroll
        for (int off = 1; off < 64; off <<= 1) {
            const int nb = __shfl_up(pre, off, 64);
            if (lane >= off) pre += nb;
        }
        int p = pre - c;
        const int cb = (lane >> 2) * 256 + (lane & 3);
        while (m) {
            const int bpos = __ffsll((unsigned long long)m) - 1;
            if (p < CAP) idx_l[p] = cb + 4 * bpos;
            ++p;
            m &= m - 1;
        }
        if (lane == 63) cnt = pre;
    }
    __syncthreads();

    const int count = min(cnt, CAP);
    const int cpad  = (count + 7) & ~7;

    if (t < count) {
        const int j = idx_l[t];
        const float4 sv = *(const float4*)(sd + (size_t)i * 8);       // src, 4 heads
        const float4 dv = *(const float4*)(sd + (size_t)j * 8 + 4);   // dst, 4 heads
        const float s0 = sv.x + dv.x, s1 = sv.y + dv.y;
        const float s2 = sv.z + dv.z, s3 = sv.w + dv.w;
        sc[0][t] = (s0 >= 0.f) ? s0 : 0.2f * s0;
        sc[1][t] = (s1 >= 0.f) ? s1 : 0.2f * s1;
        sc[2][t] = (s2 >= 0.f) ? s2 : 0.2f * s2;
        sc[3][t] = (s3 >= 0.f) ? s3 : 0.2f * s3;
    } else if (t < cpad) {
        idx_l[t] = 0;
#pragma unroll
        for (int hh = 0; hh < NH; ++hh) sc[hh][t] = 0.f;
    }
    __syncthreads();

    {
        float m = -3.4e38f;
        for (int p = lane; p < count; p += 64) m = fmaxf(m, sc[wv][p]);
#pragma unroll
        for (int off = 32; off >= 1; off >>= 1) m = fmaxf(m, __shfl_xor(m, off, 64));
        float e = 0.f;
        for (int p = lane; p < count; p += 64) {
            const float v = __expf(sc[wv][p] - m);
            sc[wv][p] = v;
            e += v;
        }
#pragma unroll
        for (int off = 32; off >= 1; off >>= 1) e += __shfl_xor(e, off, 64);
        if (lane == 0) inv_sum[wv] = 1.f / e;
    }
    __syncthreads();

    // gather from bf16 hb (128 B/row coalesced), 8 rows in flight
    float accv = 0.f;
    const unsigned short* hp = hb + (size_t)(wv * NN) * FOUT + lane;
    for (int p0 = 0; p0 < cpad; p0 += 8) {
        int jj[8]; unsigned short vv[8]; float ww[8];
#pragma unroll
        for (int k = 0; k < 8; ++k) jj[k] = idx_l[p0 + k];
#pragma unroll
        for (int k = 0; k < 8; ++k) vv[k] = hp[(size_t)jj[k] * FOUT];
#pragma unroll
        for (int k = 0; k < 8; ++k) ww[k] = sc[wv][p0 + k];
#pragma unroll
        for (int k = 0; k < 8; ++k) accv = fmaf(ww[k], bf2f(vv[k]), accv);
    }
    out[(size_t)i * (NH * FOUT) + wv * FOUT + lane] = accv * inv_sum[wv] + bias[lane];
}

extern "C" void kernel_launch(void* const* d_in, const int* in_sizes, int n_in,
                              void* d_out, int out_size, void* d_ws, size_t ws_size,
                              hipStream_t stream) {
    const float* h     = (const float*)d_in[0];
    const int*   adj   = (const int*)d_in[1];
    const float* w     = (const float*)d_in[2];
    const float* a_src = (const float*)d_in[3];
    const float* a_dst = (const float*)d_in[4];
    const float* bias  = (const float*)d_in[5];
    float* out = (float*)d_out;

    unsigned short* hb = (unsigned short*)d_ws;                 // 2 MB bf16 h'
    float* sd          = (float*)(hb + (size_t)NH * NN * FOUT); // NN*8 floats
    unsigned long long* bits = (unsigned long long*)(sd + (size_t)NN * 8); // 2 MB

    gat_prep<<<MFB + CPB, 256, 0, stream>>>(h, adj, w, a_src, a_dst, hb, sd, bits);
    gat_attn<<<NN, 256, 0, stream>>>(bits, hb, sd, bias, out);
}